// Round 7
// baseline (203.477 us; speedup 1.0000x reference)
//
#include <hip/hip_runtime.h>

// LinearAttention: out[b,n,v] = sum_k q[b,k,n] * ktv[b,k,v],
//                  ktv[b,k,v] = sum_n K[b,n,k] * V[b,n,v]
// B=16, DK=64, N=8192, DV=64, fp32.
//
// R7 = R6 resubmit (R6 hit a GPU-broker timeout; no measurement).
// R6: NO LDS in hot loops. Every K/V/q byte is consumed by exactly one
// 8-lane broadcast group of one wave -> staging through LDS was pure
// overhead (2x byte movement + 64KB/block -> 2 blocks/CU -> 8 waves/CU).
// Direct global dwordx4 loads (8 lanes share a 16B segment; HW coalesces
// to 128B unique/instr), compiler-pipelined, zero barriers in-loop.
// Occupancy now VGPR-bound (~16 waves/CU).
//  - p1: grid (64,16), 32 rows/wave; 16KB LDS used only for a staged
//    3-barrier cross-wave reduction in the epilogue.
//  - p2: grid (64,16), per-lane 4n x 8v tile; k-loop 64, 3 loads + 32 FMA.
// Floors: p1 80.25 MB -> 12.7 us; reduce 16.25 MB -> 3 us; p2 64 MB -> 10.2 us.

#define B_   16
#define N_   8192
#define DK_  64
#define DV_  64
#define CH_  64      // p1 chunks; 128 rows/block, 32 rows/wave

// ---------------- Phase 1: partial K^T V ----------------
__global__ __launch_bounds__(256) void p1_partial(
    const float* __restrict__ K, const float* __restrict__ V,
    float* __restrict__ part)
{
    __shared__ float red[4096];   // 16 KB, epilogue only

    const int c = blockIdx.x, b = blockIdx.y, t = threadIdx.x;
    const int w = t >> 6, lane = t & 63;
    const int kk = (lane >> 3) * 8;   // 8 k-groups of 8
    const int vv = (lane & 7) * 8;    // 8 v-groups of 8

    const size_t row0 = (size_t)b * N_ + (size_t)c * 128 + (size_t)w * 32;
    const float* Kl = K + row0 * DK_ + kk;   // per-lane base
    const float* Vl = V + row0 * DV_ + vv;

    float acc[8][8] = {};
    #pragma unroll 4
    for (int n = 0; n < 32; ++n) {
        alignas(16) float fk[8], fv[8];
        *(float4*)&fk[0] = *(const float4*)(Kl + n * 64);
        *(float4*)&fk[4] = *(const float4*)(Kl + n * 64 + 4);
        *(float4*)&fv[0] = *(const float4*)(Vl + n * 64);
        *(float4*)&fv[4] = *(const float4*)(Vl + n * 64 + 4);
        #pragma unroll
        for (int i = 0; i < 8; ++i)
            #pragma unroll
            for (int j = 0; j < 8; ++j)
                acc[i][j] += fk[i] * fv[j];
    }

    // staged cross-wave reduction in 16 KB LDS (epilogue; 4 barriers total)
    if (w == 0) {
        #pragma unroll
        for (int i = 0; i < 8; ++i) {
            *(float4*)&red[(kk + i) * 64 + vv]     = make_float4(acc[i][0], acc[i][1], acc[i][2], acc[i][3]);
            *(float4*)&red[(kk + i) * 64 + vv + 4] = make_float4(acc[i][4], acc[i][5], acc[i][6], acc[i][7]);
        }
    }
    __syncthreads();
    #pragma unroll
    for (int ww = 1; ww < 4; ++ww) {
        if (w == ww) {
            #pragma unroll
            for (int i = 0; i < 8; ++i) {
                float4 r0 = *(float4*)&red[(kk + i) * 64 + vv];
                float4 r1 = *(float4*)&red[(kk + i) * 64 + vv + 4];
                r0.x += acc[i][0]; r0.y += acc[i][1]; r0.z += acc[i][2]; r0.w += acc[i][3];
                r1.x += acc[i][4]; r1.y += acc[i][5]; r1.z += acc[i][6]; r1.w += acc[i][7];
                *(float4*)&red[(kk + i) * 64 + vv]     = r0;
                *(float4*)&red[(kk + i) * 64 + vv + 4] = r1;
            }
        }
        __syncthreads();
    }

    float4* P = (float4*)(part + ((size_t)c * B_ + b) * 4096);
    #pragma unroll
    for (int j = 0; j < 4; ++j)
        P[t + 256 * j] = ((const float4*)red)[t + 256 * j];
}

// ---------------- Phase 1b: reduce 64 partials -> ktv ----------------
// grid 256 x 256: one float per thread (65536 outputs), coalesced.
__global__ __launch_bounds__(256) void p1_reduce(
    const float* __restrict__ part, float* __restrict__ ktv)
{
    const int idx = blockIdx.x * 256 + threadIdx.x;   // [0, 65536)
    float s = 0.f;
    #pragma unroll
    for (int c = 0; c < CH_; ++c)
        s += part[(size_t)c * 65536 + idx];
    ktv[idx] = s;
}

// ---------------- Phase 2: out = q^T ktv ----------------
// grid (64, 16), 256 threads (4 waves). Wave w: 32 n at nb*128+w*32.
// Per-lane tile 4n x 8v; k-loop 64 with direct loads (q broadcast-8,
// ktv broadcast-8, L1/L2-resident). No LDS at all.
__global__ __launch_bounds__(256) void p2(
    const float* __restrict__ q, const float* __restrict__ ktv,
    float* __restrict__ out)
{
    const int nb = blockIdx.x, b = blockIdx.y, t = threadIdx.x;
    const int w = t >> 6, lane = t & 63;
    const int nl = (lane >> 3) * 4;  // 8 n-groups of 4
    const int vl = (lane & 7) * 8;   // 8 v-groups of 8
    const int n0 = nb * 128 + w * 32;

    const float* ql = q + (size_t)b * DK_ * N_ + n0 + nl;   // + k*N_
    const float* kl = ktv + (size_t)b * 4096 + vl;          // + k*64

    float acc[4][8] = {};
    #pragma unroll 4
    for (int k = 0; k < 64; ++k) {
        alignas(16) float fq[4], fv[8];
        *(float4*)&fq[0] = *(const float4*)(ql + (size_t)k * N_);
        *(float4*)&fv[0] = *(const float4*)(kl + k * 64);
        *(float4*)&fv[4] = *(const float4*)(kl + k * 64 + 4);
        #pragma unroll
        for (int i = 0; i < 4; ++i)
            #pragma unroll
            for (int j = 0; j < 8; ++j)
                acc[i][j] += fq[i] * fv[j];
    }

    float* ob = out + ((size_t)b * N_ + n0 + nl) * DV_ + vl;
    #pragma unroll
    for (int i = 0; i < 4; ++i) {
        *(float4*)&ob[(size_t)i * DV_]     = make_float4(acc[i][0], acc[i][1], acc[i][2], acc[i][3]);
        *(float4*)&ob[(size_t)i * DV_ + 4] = make_float4(acc[i][4], acc[i][5], acc[i][6], acc[i][7]);
    }
}

extern "C" void kernel_launch(void* const* d_in, const int* in_sizes, int n_in,
                              void* d_out, int out_size, void* d_ws, size_t ws_size,
                              hipStream_t stream)
{
    (void)in_sizes; (void)n_in; (void)out_size; (void)ws_size;
    const float* q = (const float*)d_in[0];   // [16, 64, 8192]
    const float* k = (const float*)d_in[1];   // [16, 8192, 64]
    const float* v = (const float*)d_in[2];   // [16, 8192, 64]
    float* out = (float*)d_out;               // [16, 8192, 64]

    // ws: [64][16][4096] partials (16 MB) + [16][4096] ktv (256 KB)
    float* part = (float*)d_ws;
    float* ktv  = part + (size_t)CH_ * B_ * 4096;

    p1_partial<<<dim3(CH_, B_), 256, 0, stream>>>(k, v, part);
    p1_reduce<<<dim3(256), 256, 0, stream>>>(part, ktv);
    p2<<<dim3(64, B_), 256, 0, stream>>>(q, ktv, out);
}

// Round 8
// 150.022 us; speedup vs baseline: 1.3563x; 1.3563x over previous
//
#include <hip/hip_runtime.h>

// LinearAttention: out[b,n,v] = sum_k q[b,k,n] * ktv[b,k,v],
//                  ktv[b,k,v] = sum_n K[b,n,k] * V[b,n,v]
// B=16, DK=64, N=8192, DV=64, fp32.
//
// R8: R4 (best, 151.7) + occupancy fix + load-batching fix.
//  - R7 post-mortem: no-LDS flat loop -> 32 VGPR, 1-2 loads in flight,
//    latency-bound (VALUBusy 14%). LDS staging's value = 16-deep batches.
//  - p1: wave-private staging kept, region halved to 8 KB/wave -> 32 KB
//    block -> 4 blocks/CU (16 waves/CU, was 8). Grid 1024. No in-loop
//    barriers (per-wave DS ordering).
//  - p2: ktv in 16 KB shared LDS (real reuse); q streamed direct to
//    registers in explicit 16-deep float4 batches (one vmcnt batch per
//    16 k-iters); no q LDS round-trip. Grid 1024, ~16 waves/CU.
// Floors: p1 80 MB -> 12.7 us; reduce 16.25 MB -> 3 us; p2 64 MB -> 10.2 us.

#define B_   16
#define N_   8192
#define DK_  64
#define DV_  64
#define CH_  64      // p1 chunks; 128 rows/block, 32 rows/wave, 2 rounds of 16

// ---------------- Phase 1: partial K^T V ----------------
// grid (64, 16), 256 threads (4 waves). Wave w rows [w*32, w*32+32).
__global__ __launch_bounds__(256) void p1_partial(
    const float* __restrict__ K, const float* __restrict__ V,
    float* __restrict__ part)
{
    __shared__ float sm[4][2048];   // 32 KB; wave w: K rows [0..1023], V rows [1024..2047]

    const int c = blockIdx.x, b = blockIdx.y, t = threadIdx.x;
    const int w = t >> 6, lane = t & 63;
    const int kk = (lane >> 3) * 8;   // 8 k-groups of 8
    const int vv = (lane & 7) * 8;    // 8 v-groups of 8
    float* Ksw = &sm[w][0];
    float* Vsw = &sm[w][1024];

    const size_t row0 = (size_t)b * N_ + (size_t)c * 128 + (size_t)w * 32;
    const float4* K4 = (const float4*)(K + row0 * DK_);   // 512 float4 (32 rows)
    const float4* V4 = (const float4*)(V + row0 * DV_);

    float acc[8][8] = {};

    #pragma unroll
    for (int r = 0; r < 2; ++r) {
        // batch 8 global loads (16 rows K + 16 rows V), then LDS-write
        float4 kb_[4], vb_[4];
        #pragma unroll
        for (int j = 0; j < 4; ++j) kb_[j] = K4[r * 256 + j * 64 + lane];
        #pragma unroll
        for (int j = 0; j < 4; ++j) vb_[j] = V4[r * 256 + j * 64 + lane];
        #pragma unroll
        for (int j = 0; j < 4; ++j) {
            ((float4*)Ksw)[j * 64 + lane] = kb_[j];
            ((float4*)Vsw)[j * 64 + lane] = vb_[j];
        }
        // wave-private: no barrier; compiler lgkmcnt covers ds_write->ds_read
        #pragma unroll 4
        for (int n = 0; n < 16; ++n) {
            alignas(16) float fk[8], fv[8];
            *(float4*)&fk[0] = *(const float4*)&Ksw[n * 64 + kk];
            *(float4*)&fk[4] = *(const float4*)&Ksw[n * 64 + kk + 4];
            *(float4*)&fv[0] = *(const float4*)&Vsw[n * 64 + vv];
            *(float4*)&fv[4] = *(const float4*)&Vsw[n * 64 + vv + 4];
            #pragma unroll
            for (int i = 0; i < 8; ++i)
                #pragma unroll
                for (int j = 0; j < 8; ++j)
                    acc[i][j] += fk[i] * fv[j];
        }
    }

    // epilogue: staged cross-wave reduce in red[4096] (= sm[0..1] reused).
    // Barrier FIRST: red aliases waves 0/1 tile regions still being read.
    __syncthreads();
    float* red = &sm[0][0];
    if (w == 0) {
        #pragma unroll
        for (int i = 0; i < 8; ++i) {
            *(float4*)&red[(kk + i) * 64 + vv]     = make_float4(acc[i][0], acc[i][1], acc[i][2], acc[i][3]);
            *(float4*)&red[(kk + i) * 64 + vv + 4] = make_float4(acc[i][4], acc[i][5], acc[i][6], acc[i][7]);
        }
    }
    __syncthreads();
    #pragma unroll
    for (int ww = 1; ww < 4; ++ww) {
        if (w == ww) {
            #pragma unroll
            for (int i = 0; i < 8; ++i) {
                float4 r0 = *(float4*)&red[(kk + i) * 64 + vv];
                float4 r1 = *(float4*)&red[(kk + i) * 64 + vv + 4];
                r0.x += acc[i][0]; r0.y += acc[i][1]; r0.z += acc[i][2]; r0.w += acc[i][3];
                r1.x += acc[i][4]; r1.y += acc[i][5]; r1.z += acc[i][6]; r1.w += acc[i][7];
                *(float4*)&red[(kk + i) * 64 + vv]     = r0;
                *(float4*)&red[(kk + i) * 64 + vv + 4] = r1;
            }
        }
        __syncthreads();
    }

    float4* P = (float4*)(part + ((size_t)c * B_ + b) * 4096);
    #pragma unroll
    for (int j = 0; j < 4; ++j)
        P[t + 256 * j] = ((const float4*)red)[t + 256 * j];
}

// ---------------- Phase 1b: reduce 64 partials -> ktv ----------------
// grid 256 x 256: one float per thread (65536 outputs), coalesced.
__global__ __launch_bounds__(256) void p1_reduce(
    const float* __restrict__ part, float* __restrict__ ktv)
{
    const int idx = blockIdx.x * 256 + threadIdx.x;   // [0, 65536)
    float s = 0.f;
    #pragma unroll 16
    for (int c = 0; c < CH_; ++c)
        s += part[(size_t)c * 65536 + idx];
    ktv[idx] = s;
}

// ---------------- Phase 2: out = q^T ktv ----------------
// grid (64, 16), 256 threads (4 waves). Wave w: 32 n at nb*128+w*32.
// ktv in LDS (reused 128x); q streamed direct in 16-deep float4 batches.
__global__ __launch_bounds__(256) void p2(
    const float* __restrict__ q, const float* __restrict__ ktv,
    float* __restrict__ out)
{
    __shared__ float ks[4096];       // 16 KB: ktv[b], [k][v]

    const int nb = blockIdx.x, b = blockIdx.y, t = threadIdx.x;
    const int w = t >> 6, lane = t & 63;
    const int nl = (lane >> 3) * 4;  // 8 n-groups of 4
    const int vl = (lane & 7) * 8;   // 8 v-groups of 8
    const int n0 = nb * 128 + w * 32;

    const float4* kt4 = (const float4*)(ktv + (size_t)b * 4096);
    #pragma unroll
    for (int j = 0; j < 4; ++j)
        ((float4*)ks)[t + 256 * j] = kt4[t + 256 * j];
    __syncthreads();

    const float* ql = q + (size_t)b * DK_ * N_ + n0 + nl;   // + k*N_

    float acc[4][8] = {};
    #pragma unroll
    for (int kb = 0; kb < 4; ++kb) {
        // one 16-deep vmcnt batch of q rows kb*16..kb*16+15
        alignas(16) float fq[16][4];
        #pragma unroll
        for (int u = 0; u < 16; ++u)
            *(float4*)&fq[u][0] = *(const float4*)(ql + (size_t)(kb * 16 + u) * N_);
        #pragma unroll
        for (int u = 0; u < 16; ++u) {
            const int k = kb * 16 + u;
            alignas(16) float fv[8];
            *(float4*)&fv[0] = *(const float4*)&ks[k * 64 + vl];
            *(float4*)&fv[4] = *(const float4*)&ks[k * 64 + vl + 4];
            #pragma unroll
            for (int i = 0; i < 4; ++i)
                #pragma unroll
                for (int j = 0; j < 8; ++j)
                    acc[i][j] += fq[u][i] * fv[j];
        }
    }

    float* ob = out + ((size_t)b * N_ + n0 + nl) * DV_ + vl;
    #pragma unroll
    for (int i = 0; i < 4; ++i) {
        *(float4*)&ob[(size_t)i * DV_]     = make_float4(acc[i][0], acc[i][1], acc[i][2], acc[i][3]);
        *(float4*)&ob[(size_t)i * DV_ + 4] = make_float4(acc[i][4], acc[i][5], acc[i][6], acc[i][7]);
    }
}

extern "C" void kernel_launch(void* const* d_in, const int* in_sizes, int n_in,
                              void* d_out, int out_size, void* d_ws, size_t ws_size,
                              hipStream_t stream)
{
    (void)in_sizes; (void)n_in; (void)out_size; (void)ws_size;
    const float* q = (const float*)d_in[0];   // [16, 64, 8192]
    const float* k = (const float*)d_in[1];   // [16, 8192, 64]
    const float* v = (const float*)d_in[2];   // [16, 8192, 64]
    float* out = (float*)d_out;               // [16, 8192, 64]

    // ws: [64][16][4096] partials (16 MB) + [16][4096] ktv (256 KB)
    float* part = (float*)d_ws;
    float* ktv  = part + (size_t)CH_ * B_ * 4096;

    p1_partial<<<dim3(CH_, B_), 256, 0, stream>>>(k, v, part);
    p1_reduce<<<dim3(256), 256, 0, stream>>>(part, ktv);
    p2<<<dim3(64, B_), 256, 0, stream>>>(q, ktv, out);
}